// Round 1
// baseline (365.472 us; speedup 1.0000x reference)
//
#include <hip/hip_runtime.h>
#include <math.h>

// CapsuleLayer dynamic routing, fp32.
// B=256 batch, I=2048 input capsules, K=8 input dim, J=10 output capsules, D=16 output dim.
// Strategy: never materialize u_hat [B,J,I,D] (320 MB). Recompute U_i = W[:,i]@x[b,i]
// (J*D*K = 1280 MACs) per (b,i) per round in registers. Routing logits are linear in the
// accumulated squashed outputs: after round r, logits = (v1+...+vr) . U  -- so only a
// running v_sum [B,J,D] is kept (no logit buffer).
//
// ws layout: s_acc float[B*J*D] | v_buf float[B*J*D]  (total 320 KB)

#define BB 256
#define II 2048
#define KK 8
#define JJ 10
#define DD 16
#define IT 32   // i's per block in routing kernels
#define BT 16   // b's per block (one per 16-lane d-group)

__global__ __launch_bounds__(256) void zero_kernel(float* __restrict__ p, int n) {
    int idx = blockIdx.x * blockDim.x + threadIdx.x;
    if (idx < n) p[idx] = 0.f;
}

// Round 1: c = 1/J uniform (softmax of zeros). Accumulate sum_i U into s_acc;
// the 1/J is applied as `scale` in the squash kernel.
__global__ __launch_bounds__(256) void round1_kernel(
    const float* __restrict__ x, const float* __restrict__ W,
    float* __restrict__ s_acc)
{
    const int t  = threadIdx.x;
    const int d  = t & 15;
    const int bq = t >> 4;                 // 0..15
    const int b  = blockIdx.y * BT + bq;
    const int i0 = blockIdx.x * IT;

    float acc[JJ];
#pragma unroll
    for (int j = 0; j < JJ; ++j) acc[j] = 0.f;

    for (int ii = 0; ii < IT; ++ii) {
        const int i = i0 + ii;
        const float* xp = x + ((b * II) + i) * KK;
        const float4 xa = *(const float4*)(xp);
        const float4 xb = *(const float4*)(xp + 4);
#pragma unroll
        for (int j = 0; j < JJ; ++j) {
            const float* wp = W + (((j * II + i) * DD + d) * KK);
            const float4 w0 = *(const float4*)(wp);
            const float4 w1 = *(const float4*)(wp + 4);
            float u = w0.x*xa.x + w0.y*xa.y + w0.z*xa.z + w0.w*xa.w
                    + w1.x*xb.x + w1.y*xb.y + w1.z*xb.z + w1.w*xb.w;
            acc[j] += u;
        }
    }
#pragma unroll
    for (int j = 0; j < JJ; ++j)
        atomicAdd(&s_acc[(b * JJ + j) * DD + d], acc[j]);
}

// Rounds 2 and 3: logits_j = sum_d v[b,j,d]*U[j,d]  (v = running sum of squashed outputs),
// softmax over j, accumulate c_j * U[j,d] into s_acc.
__global__ __launch_bounds__(256) void round_kernel(
    const float* __restrict__ x, const float* __restrict__ W,
    const float* __restrict__ v, float* __restrict__ s_acc)
{
    const int t  = threadIdx.x;
    const int d  = t & 15;
    const int bq = t >> 4;
    const int b  = blockIdx.y * BT + bq;
    const int i0 = blockIdx.x * IT;

    float vr[JJ], acc[JJ];
#pragma unroll
    for (int j = 0; j < JJ; ++j) {
        vr[j]  = v[(b * JJ + j) * DD + d];
        acc[j] = 0.f;
    }

    for (int ii = 0; ii < IT; ++ii) {
        const int i = i0 + ii;
        const float* xp = x + ((b * II) + i) * KK;
        const float4 xa = *(const float4*)(xp);
        const float4 xb = *(const float4*)(xp + 4);

        float U[JJ], L[JJ];
#pragma unroll
        for (int j = 0; j < JJ; ++j) {
            const float* wp = W + (((j * II + i) * DD + d) * KK);
            const float4 w0 = *(const float4*)(wp);
            const float4 w1 = *(const float4*)(wp + 4);
            U[j] = w0.x*xa.x + w0.y*xa.y + w0.z*xa.z + w0.w*xa.w
                 + w1.x*xb.x + w1.y*xb.y + w1.z*xb.z + w1.w*xb.w;
            L[j] = vr[j] * U[j];
        }
        // reduce logits over the 16 d-lanes (d-groups are 16 contiguous lanes in a wave)
#pragma unroll
        for (int m = 8; m >= 1; m >>= 1) {
#pragma unroll
            for (int j = 0; j < JJ; ++j)
                L[j] += __shfl_xor(L[j], m, 64);
        }
        // softmax over j, fully in-register (redundant across the 16 lanes, fine)
        float mx = L[0];
#pragma unroll
        for (int j = 1; j < JJ; ++j) mx = fmaxf(mx, L[j]);
        float sum = 0.f;
#pragma unroll
        for (int j = 0; j < JJ; ++j) { L[j] = __expf(L[j] - mx); sum += L[j]; }
        const float inv = 1.f / sum;
#pragma unroll
        for (int j = 0; j < JJ; ++j) acc[j] += (L[j] * inv) * U[j];
    }
#pragma unroll
    for (int j = 0; j < JJ; ++j)
        atomicAdd(&s_acc[(b * JJ + j) * DD + d], acc[j]);
}

// v_out = squash(scale * s_acc); optionally accumulate into dst; optionally zero s_acc
// for the next routing round.
__global__ __launch_bounds__(256) void squash_kernel(
    float* __restrict__ s_acc, float* __restrict__ dst,
    float scale, int add_to_dst, int zero_src)
{
    int idx = blockIdx.x * blockDim.x + threadIdx.x;
    if (idx >= BB * JJ) return;
    float s[DD];
    float ss = 0.f;
#pragma unroll
    for (int d0 = 0; d0 < DD; ++d0) {
        s[d0] = s_acc[idx * DD + d0] * scale;
        ss += s[d0] * s[d0];
    }
    const float coef = ss / (1.f + ss) / sqrtf(ss + 1e-7f);
#pragma unroll
    for (int d0 = 0; d0 < DD; ++d0) {
        const float vv = coef * s[d0];
        if (add_to_dst) dst[idx * DD + d0] += vv;
        else            dst[idx * DD + d0] = vv;
        if (zero_src)   s_acc[idx * DD + d0] = 0.f;
    }
}

extern "C" void kernel_launch(void* const* d_in, const int* in_sizes, int n_in,
                              void* d_out, int out_size, void* d_ws, size_t ws_size,
                              hipStream_t stream) {
    const float* x = (const float*)d_in[0];   // [B, I, K]
    const float* W = (const float*)d_in[1];   // [J, I, D, K]
    float* out   = (float*)d_out;             // [B, J, D]
    float* s_acc = (float*)d_ws;              // [B*J*D]
    float* v_buf = s_acc + BB * JJ * DD;      // [B*J*D]

    const int NS = BB * JJ * DD;              // 40960
    dim3 rg(II / IT, BB / BT);                // 64 x 16 blocks

    zero_kernel<<<(NS + 255) / 256, 256, 0, stream>>>(s_acc, NS);

    // round 1: s = (1/J) * sum_i U ; v1 = squash(s)
    round1_kernel<<<rg, 256, 0, stream>>>(x, W, s_acc);
    squash_kernel<<<(BB * JJ + 255) / 256, 256, 0, stream>>>(s_acc, v_buf, 0.1f, 0, 1);

    // round 2: logits = v1 . U
    round_kernel<<<rg, 256, 0, stream>>>(x, W, v_buf, s_acc);
    squash_kernel<<<(BB * JJ + 255) / 256, 256, 0, stream>>>(s_acc, v_buf, 1.0f, 1, 1);

    // round 3: logits = (v1+v2) . U  (logits are linear in accumulated v)
    round_kernel<<<rg, 256, 0, stream>>>(x, W, v_buf, s_acc);
    squash_kernel<<<(BB * JJ + 255) / 256, 256, 0, stream>>>(s_acc, out, 1.0f, 0, 0);
}